// Round 1
// 1075.216 us; speedup vs baseline: 1.0604x; 1.0604x over previous
//
#include <hip/hip_runtime.h>

// Problem constants
#define BB 64
#define UU 1024
#define HH 16
#define MM 512
#define DD 4
#define NR 8208   // H*(M+1)
#define NW 8192   // H*M
#define NK 1024   // U
#define BH  (BB * HH)        // 1024
#define BHM (BB * HH * MM)   // 524288
#define BU  (BB * UU)        // 65536
#define MCC 16               // column-sum partial chunks (M/MCC = 32 rows each)

// ---------------------------------------------------------------------------
// Algebraic restructure (vs. materialized per-layer memory updates):
//   mem_l = P_l * mem0 + sum_j Q_{l,j} * nv_j        (per (b,m,h) scalars)
//   P_l   = prod_{j<l} (1 - ww_j)
//   Q_{l,j} = ww_j * prod_{j<i<l} (1 - ww_i)
// colsum_l[b,u] = sum_m P_l*mem0   + sum_j S_{l,j}[b,h]*nv_j[b,u]
// read_l[b,u]   = sum_m rw*P_l*mem0 + sum_j R_{l,j}[b,h]*nv_j[b,u] + rw[M]*out
// with S_{l,j} = sum_m Q_{l,j},  R_{l,j} = sum_m rw_l*Q_{l,j}.
// mem0 stays read-only (clean, L3-resident); memory is written ONCE (k_final).
// ---------------------------------------------------------------------------

__device__ inline float warp_reduce_max(float v) {
    #pragma unroll
    for (int off = 32; off > 0; off >>= 1) v = fmaxf(v, __shfl_xor(v, off));
    return v;
}
__device__ inline float warp_reduce_sum(float v) {
    #pragma unroll
    for (int off = 32; off > 0; off >>= 1) v += __shfl_xor(v, off);
    return v;
}

// part[mc][b][u] = sum_{m in chunk mc} wt[b,h(u),m] * mem0[b,m,u]   (wt==null -> 1)
// grid (B, MCC), block 256, float4 per thread (u = 4t, h = t>>4)
__global__ __launch_bounds__(256) void k_cpass(const float* __restrict__ mem,
                                               const float* __restrict__ wt,
                                               float* __restrict__ part) {
    const int b = blockIdx.x, mc = blockIdx.y, t = threadIdx.x;
    const int h = t >> 4;
    const float4* src = (const float4*)(mem + (size_t)b * MM * UU);
    float4 s = make_float4(0.f, 0.f, 0.f, 0.f);
    const int m0 = mc * 32;
    if (wt) {
        const float* w = wt + (size_t)(b * HH + h) * MM;
        for (int m = m0; m < m0 + 32; ++m) {
            float g = w[m];
            float4 v = src[(size_t)m * 256 + t];
            s.x = fmaf(g, v.x, s.x); s.y = fmaf(g, v.y, s.y);
            s.z = fmaf(g, v.z, s.z); s.w = fmaf(g, v.w, s.w);
        }
    } else {
        for (int m = m0; m < m0 + 32; ++m) {
            float4 v = src[(size_t)m * 256 + t];
            s.x += v.x; s.y += v.y; s.z += v.z; s.w += v.w;
        }
    }
    *(float4*)(part + ((size_t)(mc * BB + b) << 10) + t * 4) = s;
}

// ---------------------------------------------------------------------------
// Skinny GEMM with fused A-staging:
//   if parts != null:  A[r][u] = (g*Abase[r][u] + sum_mc parts[mc][r][u]
//                                 + sum_{j<ncoef} coefs[j][r,h]*nvall[j][r][u]) * scale
//   else:              A = Abase
// block 256 (4 waves), block tile 64 rows x 128 cols; K-split over blockIdx.y;
// partials to pbuf[ks][64][N]. Dynamic LDS = kchunk*64*4 bytes.
// ---------------------------------------------------------------------------
__global__ __launch_bounds__(256) void k_gemm(const float* __restrict__ Abase,
                                              const float* __restrict__ parts,
                                              const float* __restrict__ coefs, int ncoef,
                                              const float* __restrict__ nvall,
                                              const float* __restrict__ gvec, float scale,
                                              const float* __restrict__ W,
                                              float* __restrict__ pbuf,
                                              int N, int kchunk, int kcl2) {
    extern __shared__ float At[];   // At[kk][r], kchunk x 64
    const int t = threadIdx.x;
    const int cb = blockIdx.x * 128;
    const int ks = blockIdx.y;
    const int kbase = ks * kchunk;

    const int n4 = kchunk >> 4;              // float4 staging loads per thread
    const int kq_mask = (kchunk >> 2) - 1;
    for (int i = 0; i < n4; ++i) {
        int idx4 = t + (i << 8);
        int r = idx4 >> kcl2;
        int kq = idx4 & kq_mask;
        int u = kbase + (kq << 2);
        float4 v;
        if (parts) {
            float4 o = *(const float4*)(Abase + r * UU + u);
            const int h = u >> 6;
            float g = gvec ? gvec[r * HH + h] : 1.0f;
            v.x = g * o.x; v.y = g * o.y; v.z = g * o.z; v.w = g * o.w;
            for (int mc = 0; mc < MCC; ++mc) {
                const float4 p = *(const float4*)(parts + ((size_t)(mc * BB + r) << 10) + u);
                v.x += p.x; v.y += p.y; v.z += p.z; v.w += p.w;
            }
            for (int j = 0; j < ncoef; ++j) {
                float c = coefs[j * BH + r * HH + h];
                const float4 nv = *(const float4*)(nvall + ((size_t)(j * BB + r) << 10) + u);
                v.x = fmaf(c, nv.x, v.x); v.y = fmaf(c, nv.y, v.y);
                v.z = fmaf(c, nv.z, v.z); v.w = fmaf(c, nv.w, v.w);
            }
            v.x *= scale; v.y *= scale; v.z *= scale; v.w *= scale;
        } else {
            v = *(const float4*)(Abase + r * UU + u);
        }
        int kk = kq << 2;
        At[(kk + 0) * 64 + r] = v.x;
        At[(kk + 1) * 64 + r] = v.y;
        At[(kk + 2) * 64 + r] = v.z;
        At[(kk + 3) * 64 + r] = v.w;
    }
    __syncthreads();

    const int wave = t >> 6;
    const int lane = t & 63;
    const int row0 = wave << 4;
    const int col = cb + (lane << 1);
    const bool wvalid = (col + 2 <= N);
    const float* Wp = W + (size_t)kbase * N + col;

    float acc[16][2];
    #pragma unroll
    for (int r = 0; r < 16; ++r) { acc[r][0] = 0.f; acc[r][1] = 0.f; }

    float2 wb0[8], wb1[8];
    if (wvalid) {
        #pragma unroll
        for (int i = 0; i < 8; ++i) wb0[i] = *(const float2*)(Wp + (size_t)i * N);
    }
    for (int kb = 0; kb < kchunk; kb += 8) {
        if (wvalid && (kb + 8 < kchunk)) {
            #pragma unroll
            for (int i = 0; i < 8; ++i)
                wb1[i] = *(const float2*)(Wp + (size_t)(kb + 8 + i) * N);
        }
        #pragma unroll
        for (int i = 0; i < 8; ++i) {
            const float* ap = &At[(kb + i) * 64 + row0];
            float a[16];
            *(float4*)&a[0]  = *(const float4*)(ap + 0);
            *(float4*)&a[4]  = *(const float4*)(ap + 4);
            *(float4*)&a[8]  = *(const float4*)(ap + 8);
            *(float4*)&a[12] = *(const float4*)(ap + 12);
            float2 wv = wb0[i];
            #pragma unroll
            for (int r = 0; r < 16; ++r) {
                acc[r][0] = fmaf(a[r], wv.x, acc[r][0]);
                acc[r][1] = fmaf(a[r], wv.y, acc[r][1]);
            }
        }
        #pragma unroll
        for (int i = 0; i < 8; ++i) wb0[i] = wb1[i];
    }

    if (wvalid) {
        float* dst = pbuf + (size_t)ks * 64 * N + col;
        #pragma unroll
        for (int r = 0; r < 16; ++r) {
            float2 o; o.x = acc[r][0]; o.y = acc[r][1];
            *(float2*)(dst + (size_t)(row0 + r) * N) = o;
        }
    }
}

// ---------------------------------------------------------------------------
// Read-attention softmax (S = 513 slots) + fused coefficient epilogue.
// Outputs: wtbl[bh][m] = rw[m] * P_l[m]   (the rpass weight)
//          rwM[bh]     = rw[slot M]       (input-slot weight)
//          Rtab[j][bh] = sum_m rw[m]*Q_{l,j}[m]   for j < LP
// ---------------------------------------------------------------------------
template <int LP>
__global__ __launch_bounds__(256) void k_softmaxR(const float* __restrict__ pbuf,
                                                  const float* __restrict__ bias,
                                                  const float* __restrict__ wwall,
                                                  float* __restrict__ wtbl,
                                                  float* __restrict__ rwM,
                                                  float* __restrict__ Rtab) {
    __shared__ float sm[4];
    __shared__ float sr[4][4];
    const int bh = blockIdx.x;
    const int b = bh >> 4, h = bh & 15;
    const int t = threadIdx.x;

    float v[3];
    float mx = -1e30f;
    #pragma unroll
    for (int i = 0; i < 3; ++i) {
        int slot = t + (i << 8);
        float val = -1e30f;
        if (slot < MM + 1) {
            int j = slot * HH + h;
            val = bias[j];
            #pragma unroll
            for (int ks = 0; ks < 8; ++ks) val += pbuf[(size_t)(ks * BB + b) * NR + j];
        }
        v[i] = val;
        mx = fmaxf(mx, val);
    }
    mx = warp_reduce_max(mx);
    if ((t & 63) == 0) sm[t >> 6] = mx;
    __syncthreads();
    mx = fmaxf(fmaxf(sm[0], sm[1]), fmaxf(sm[2], sm[3]));
    __syncthreads();

    float sum = 0.f;
    #pragma unroll
    for (int i = 0; i < 3; ++i) {
        int slot = t + (i << 8);
        if (slot < MM + 1) { v[i] = __expf(v[i] - mx); sum += v[i]; }
    }
    sum = warp_reduce_sum(sum);
    if ((t & 63) == 0) sm[t >> 6] = sum;
    __syncthreads();
    sum = sm[0] + sm[1] + sm[2] + sm[3];
    const float inv = 1.0f / sum;

    float racc[3] = {0.f, 0.f, 0.f};
    #pragma unroll
    for (int i = 0; i < 2; ++i) {           // slots t, t+256 are all m < 512
        int m = t + (i << 8);
        float p = v[i] * inv;
        float prod = 1.f;
        if (LP > 0) {
            float w[3];
            #pragma unroll
            for (int j = 0; j < LP; ++j)
                w[j] = wwall[((size_t)j * BH + bh) * MM + m];
            #pragma unroll
            for (int j = LP - 1; j >= 0; --j) {
                racc[j] += p * (w[j] * prod);   // rw * Q_{l,j}
                prod *= (1.f - w[j]);
            }
        }
        wtbl[(size_t)bh * MM + m] = p * prod;   // rw * P_l
    }
    if (t == 0) rwM[bh] = v[2] * inv;           // slot 512 (input slot)

    if (LP > 0) {
        #pragma unroll
        for (int j = 0; j < LP; ++j) racc[j] = warp_reduce_sum(racc[j]);
        if ((t & 63) == 0) {
            #pragma unroll
            for (int j = 0; j < LP; ++j) sr[t >> 6][j] = racc[j];
        }
        __syncthreads();
        if (t < LP) Rtab[t * BH + bh] = sr[0][t] + sr[1][t] + sr[2][t] + sr[3][t];
    }
}

// ---------------------------------------------------------------------------
// Write-attention softmax (S = 512 slots) + fused coefficient epilogue.
// Outputs: wwOut[bh][m] = ww_l[m]
//   if WSP: Pout[bh][m] = P_{l+1}[m] = P_l*(1-ww_l)  (next colsum weight)
//           Stab[j][bh] = sum_m Q_{l+1,j}[m],  j <= LP
// ---------------------------------------------------------------------------
template <int LP, int WSP>
__global__ __launch_bounds__(256) void k_softmaxS(const float* __restrict__ pbuf,
                                                  const float* __restrict__ bias,
                                                  const float* __restrict__ wwall,
                                                  float* __restrict__ wwOut,
                                                  float* __restrict__ Pout,
                                                  float* __restrict__ Stab) {
    __shared__ float sm[4];
    __shared__ float sr[4][4];
    const int bh = blockIdx.x;
    const int b = bh >> 4, h = bh & 15;
    const int t = threadIdx.x;

    float v[2];
    float mx = -1e30f;
    #pragma unroll
    for (int i = 0; i < 2; ++i) {
        int slot = t + (i << 8);
        int j = slot * HH + h;
        float val = bias[j];
        #pragma unroll
        for (int ks = 0; ks < 8; ++ks) val += pbuf[(size_t)(ks * BB + b) * NW + j];
        v[i] = val;
        mx = fmaxf(mx, val);
    }
    mx = warp_reduce_max(mx);
    if ((t & 63) == 0) sm[t >> 6] = mx;
    __syncthreads();
    mx = fmaxf(fmaxf(sm[0], sm[1]), fmaxf(sm[2], sm[3]));
    __syncthreads();

    float sum = 0.f;
    #pragma unroll
    for (int i = 0; i < 2; ++i) { v[i] = __expf(v[i] - mx); sum += v[i]; }
    sum = warp_reduce_sum(sum);
    if ((t & 63) == 0) sm[t >> 6] = sum;
    __syncthreads();
    sum = sm[0] + sm[1] + sm[2] + sm[3];
    const float inv = 1.0f / sum;

    float sacc[4] = {0.f, 0.f, 0.f, 0.f};
    #pragma unroll
    for (int i = 0; i < 2; ++i) {
        int m = t + (i << 8);
        float p = v[i] * inv;
        wwOut[(size_t)bh * MM + m] = p;
        if (WSP) {
            float prod = 1.f;
            float q[3];
            if (LP > 0) {
                float w[3];
                #pragma unroll
                for (int j = 0; j < LP; ++j)
                    w[j] = wwall[((size_t)j * BH + bh) * MM + m];
                #pragma unroll
                for (int j = LP - 1; j >= 0; --j) {
                    q[j] = w[j] * prod;
                    prod *= (1.f - w[j]);
                }
            }
            float om = 1.f - p;
            #pragma unroll
            for (int j = 0; j < LP; ++j) sacc[j] += q[j] * om;   // Q_{l+1,j}, j<l
            sacc[LP] += p;                                       // Q_{l+1,l} = ww_l
            Pout[(size_t)bh * MM + m] = prod * om;               // P_{l+1}
        }
    }
    if (WSP) {
        #pragma unroll
        for (int j = 0; j <= LP; ++j) sacc[j] = warp_reduce_sum(sacc[j]);
        if ((t & 63) == 0) {
            #pragma unroll
            for (int j = 0; j <= LP; ++j) sr[t >> 6][j] = sacc[j];
        }
        __syncthreads();
        if (t <= LP) Stab[t * BH + bh] = sr[0][t] + sr[1][t] + sr[2][t] + sr[3][t];
    }
}

// newval = relu(sum_ks kpartials + bk); on last layer also write `out`.
__global__ void k_relu(const float* __restrict__ pbuf, const float* __restrict__ bk,
                       float* __restrict__ newval, float* __restrict__ outdst) {
    int i = blockIdx.x * 256 + threadIdx.x;
    int b = i >> 10, u = i & 1023;
    float v = bk[u];
    for (int ks = 0; ks < 32; ++ks) v += pbuf[(size_t)(ks * BB + b) * NK + u];
    v = fmaxf(v, 0.f);
    newval[i] = v;
    if (outdst) outdst[i] = v;
}

// memOut[b,m,u] = P_4*mem0 + sum_j Q_{4,j}*nv_j   (the ONLY memory write)
// grid (B,16), block 256 x float4
__global__ __launch_bounds__(256) void k_final(const float* __restrict__ mem0,
                                               const float* __restrict__ wwall,
                                               const float* __restrict__ nvall,
                                               float* __restrict__ dst) {
    const int b = blockIdx.x, mc = blockIdx.y, t = threadIdx.x;
    const int h = t >> 4;
    const float4* s4 = (const float4*)(mem0 + (size_t)b * MM * UU);
    float4* d4 = (float4*)(dst + (size_t)b * MM * UU);
    const float* w0 = wwall + ((size_t)(0 * BB + b) * HH + h) * MM;
    const float* w1 = wwall + ((size_t)(1 * BB + b) * HH + h) * MM;
    const float* w2 = wwall + ((size_t)(2 * BB + b) * HH + h) * MM;
    const float* w3 = wwall + ((size_t)(3 * BB + b) * HH + h) * MM;
    float4 n0 = *(const float4*)(nvall + ((size_t)(0 * BB + b) << 10) + t * 4);
    float4 n1 = *(const float4*)(nvall + ((size_t)(1 * BB + b) << 10) + t * 4);
    float4 n2 = *(const float4*)(nvall + ((size_t)(2 * BB + b) << 10) + t * 4);
    float4 n3 = *(const float4*)(nvall + ((size_t)(3 * BB + b) << 10) + t * 4);
    const int m0 = mc * 32;
    for (int m = m0; m < m0 + 32; ++m) {
        float a0 = w0[m], a1 = w1[m], a2 = w2[m], a3 = w3[m];
        float c3 = a3,        r3 = 1.f - a3;
        float c2 = a2 * r3,   r2 = (1.f - a2) * r3;
        float c1 = a1 * r2,   r1 = (1.f - a1) * r2;
        float c0 = a0 * r1,   p  = (1.f - a0) * r1;
        float4 v = s4[(size_t)m * 256 + t];
        float4 o;
        o.x = p * v.x; o.y = p * v.y; o.z = p * v.z; o.w = p * v.w;
        o.x = fmaf(c0, n0.x, o.x); o.y = fmaf(c0, n0.y, o.y);
        o.z = fmaf(c0, n0.z, o.z); o.w = fmaf(c0, n0.w, o.w);
        o.x = fmaf(c1, n1.x, o.x); o.y = fmaf(c1, n1.y, o.y);
        o.z = fmaf(c1, n1.z, o.z); o.w = fmaf(c1, n1.w, o.w);
        o.x = fmaf(c2, n2.x, o.x); o.y = fmaf(c2, n2.y, o.y);
        o.z = fmaf(c2, n2.z, o.z); o.w = fmaf(c2, n2.w, o.w);
        o.x = fmaf(c3, n3.x, o.x); o.y = fmaf(c3, n3.y, o.y);
        o.z = fmaf(c3, n3.z, o.z); o.w = fmaf(c3, n3.w, o.w);
        d4[(size_t)m * 256 + t] = o;
    }
}

// ---------------------------------------------------------------------------
extern "C" void kernel_launch(void* const* d_in, const int* in_sizes, int n_in,
                              void* d_out, int out_size, void* d_ws, size_t ws_size,
                              hipStream_t stream) {
    const float* x    = (const float*)d_in[0];
    const float* memI = (const float*)d_in[1];
    const float* Wr   = (const float*)d_in[2];
    const float* br   = (const float*)d_in[3];
    const float* Ww   = (const float*)d_in[4];
    const float* bw   = (const float*)d_in[5];
    const float* Wk   = (const float*)d_in[6];
    const float* bk   = (const float*)d_in[7];

    float* outp   = (float*)d_out;        // [B,U]
    float* memOut = outp + BB * UU;       // [B,M,U] — written ONCE at the end

    // workspace (~13.0 MB)
    float* wwAll = (float*)d_ws;          // [4][B][H][M]  ww per layer
    float* wtbl  = wwAll + 4 * BHM;       // [B][H][M]     rpass weight rw*P_l
    float* Ptbl  = wtbl + BHM;            // [B][H][M]     colsum weight P_{l+1}
    float* nvAll = Ptbl + BHM;            // [4][B][U]     newval per layer
    float* rwM   = nvAll + 4 * BU;        // [B*H]         rw[input slot]
    float* Rtab  = rwM + BH;              // [4][B*H]
    float* Stab  = Rtab + 4 * BH;         // [4][B*H]

    // scratch inside the (not-yet-written) memory output region (~25 MB of 134 MB)
    float* pbuf  = memOut;                // up to 8*64*8208 f32 (16.8 MB)
    float* wcolp = pbuf + 8 * BB * NR;    // [MCC][B][U] colsum partials
    float* rp    = wcolp + MCC * BU;      // [MCC][B][U] rpass partials

    // colsum_0 partials (weights == 1)
    k_cpass<<<dim3(BB, MCC), 256, 0, stream>>>(memI, nullptr, wcolp);

    for (int l = 0; l < DD; ++l) {
        const float* curOut = (l == 0) ? x : nvAll + (size_t)(l - 1) * BU;
        float* nv = nvAll + (size_t)l * BU;
        float* wwOut = wwAll + (size_t)l * BHM;

        // rlog = memstate @ Wr[l];  memstate staged on the fly:
        //   (sum_mc wcolp + sum_j S_j*nv_j + out) / 513
        k_gemm<<<dim3(65, 8), 256, 128 * 64 * 4, stream>>>(
            curOut, wcolp, Stab, l, nvAll, nullptr, 1.0f / 513.0f,
            Wr + (size_t)l * UU * NR, pbuf, NR, 128, 5);
        switch (l) {
            case 0: k_softmaxR<0><<<BH, 256, 0, stream>>>(pbuf, br + (size_t)l * NR, wwAll, wtbl, rwM, Rtab); break;
            case 1: k_softmaxR<1><<<BH, 256, 0, stream>>>(pbuf, br + (size_t)l * NR, wwAll, wtbl, rwM, Rtab); break;
            case 2: k_softmaxR<2><<<BH, 256, 0, stream>>>(pbuf, br + (size_t)l * NR, wwAll, wtbl, rwM, Rtab); break;
            default: k_softmaxR<3><<<BH, 256, 0, stream>>>(pbuf, br + (size_t)l * NR, wwAll, wtbl, rwM, Rtab); break;
        }
        // read-pass partials over immutable mem0, weight = rw*P_l
        k_cpass<<<dim3(BB, MCC), 256, 0, stream>>>(memI, wtbl, rp);
        // klog = kin @ Wk[l];  kin staged on the fly:
        //   sum_mc rp + sum_j R_j*nv_j + rwM*out
        k_gemm<<<dim3(8, 32), 256, 32 * 64 * 4, stream>>>(
            curOut, rp, Rtab, l, nvAll, rwM, 1.0f,
            Wk + (size_t)l * UU * NK, pbuf, NK, 32, 3);
        k_relu<<<BU / 256, 256, 0, stream>>>(pbuf, bk + (size_t)l * NK, nv,
                                             (l == DD - 1) ? outp : (float*)nullptr);
        // wlog = newval @ Ww[l]
        k_gemm<<<dim3(64, 8), 256, 128 * 64 * 4, stream>>>(
            nv, nullptr, nullptr, 0, nullptr, nullptr, 1.0f,
            Ww + (size_t)l * UU * NW, pbuf, NW, 128, 5);
        switch (l) {
            case 0: k_softmaxS<0, 1><<<BH, 256, 0, stream>>>(pbuf, bw + (size_t)l * NW, wwAll, wwOut, Ptbl, Stab); break;
            case 1: k_softmaxS<1, 1><<<BH, 256, 0, stream>>>(pbuf, bw + (size_t)l * NW, wwAll, wwOut, Ptbl, Stab); break;
            case 2: k_softmaxS<2, 1><<<BH, 256, 0, stream>>>(pbuf, bw + (size_t)l * NW, wwAll, wwOut, Ptbl, Stab); break;
            default: k_softmaxS<3, 0><<<BH, 256, 0, stream>>>(pbuf, bw + (size_t)l * NW, wwAll, wwOut, Ptbl, Stab); break;
        }
        // colsum_{l+1} partials, weight = P_{l+1}
        if (l < DD - 1)
            k_cpass<<<dim3(BB, MCC), 256, 0, stream>>>(memI, Ptbl, wcolp);
    }

    // single memory write: memOut = P_4*mem0 + sum_j Q_{4,j}*nv_j
    k_final<<<dim3(BB, 16), 256, 0, stream>>>(memI, wwAll, nvAll, memOut);
}

// Round 2
// 998.694 us; speedup vs baseline: 1.1417x; 1.0766x over previous
//
#include <hip/hip_runtime.h>

// Problem constants
#define BB 64
#define UU 1024
#define HH 16
#define MM 512
#define DD 4
#define NR 8208   // H*(M+1)
#define NW 8192   // H*M
#define NK 1024   // U
#define BH  (BB * HH)        // 1024
#define BHM (BB * HH * MM)   // 524288
#define BU  (BB * UU)        // 65536

// ---------------------------------------------------------------------------
// Algebra:  mem_l = P_l*mem0 + sum_j Q_{l,j}*nv_j   (per (b,m,h) scalars)
//   P_l = prod_{j<l}(1-ww_j),  Q_{l,j} = ww_j * prod_{j<i<l}(1-ww_i)
// kin_l[b,u]    = sum_m (rw*P_l)*mem0 + sum_j R_j*nv_j + rw[M]*out
// colsum_l[b,u] = sum_m  P_l    *mem0 + sum_j S_j*nv_j
// All weighted mem0 passes are fused INTO the softmax kernels (block (b,h)
// owns 64 columns of mem0); glue tensors never round-trip through HBM.
// mem0 is read-only (L3-resident); memory written once (k_final).
// ---------------------------------------------------------------------------

__device__ inline float warp_reduce_max(float v) {
    #pragma unroll
    for (int off = 32; off > 0; off >>= 1) v = fmaxf(v, __shfl_xor(v, off));
    return v;
}
__device__ inline float warp_reduce_sum(float v) {
    #pragma unroll
    for (int off = 32; off > 0; off >>= 1) v += __shfl_xor(v, off);
    return v;
}

// colsum0[b,u] = sum_m mem0[b,m,u]   grid (B,4), block 256
__global__ __launch_bounds__(256) void k_colsum0(const float* __restrict__ mem0,
                                                 float* __restrict__ colsum) {
    __shared__ float4 red[4][64];
    const int b = blockIdx.x, uc = blockIdx.y, t = threadIdx.x;
    const int tu = t & 63, tg = t >> 6;
    const float4* src = (const float4*)(mem0 + (size_t)b * MM * UU);
    const int col4 = uc * 64 + tu;
    float4 s = make_float4(0.f, 0.f, 0.f, 0.f);
    for (int m = tg * 128; m < tg * 128 + 128; ++m) {
        float4 v = src[(size_t)m * 256 + col4];
        s.x += v.x; s.y += v.y; s.z += v.z; s.w += v.w;
    }
    red[tg][tu] = s;
    __syncthreads();
    if (t < 64) {
        float4 a = red[0][t], o;
        o.x = a.x + red[1][t].x + red[2][t].x + red[3][t].x;
        o.y = a.y + red[1][t].y + red[2][t].y + red[3][t].y;
        o.z = a.z + red[1][t].z + red[2][t].z + red[3][t].z;
        o.w = a.w + red[1][t].w + red[2][t].w + red[3][t].w;
        *(float4*)(colsum + (size_t)b * UU + uc * 256 + t * 4) = o;
    }
}

// ---------------------------------------------------------------------------
// Skinny GEMM, fused simple staging: A = (Abase [+ Badd]) * scale
// block 256 (4 waves), tile 64 rows x 128 cols; K-split over blockIdx.y;
// partials to pbuf[ks][64][N]. Dynamic LDS = kchunk*64*4 bytes.
// ---------------------------------------------------------------------------
__global__ __launch_bounds__(256) void k_gemm(const float* __restrict__ Abase,
                                              const float* __restrict__ Badd,
                                              float scale,
                                              const float* __restrict__ W,
                                              float* __restrict__ pbuf,
                                              int N, int kchunk, int kcl2) {
    extern __shared__ float At[];   // At[kk][r], kchunk x 64
    const int t = threadIdx.x;
    const int cb = blockIdx.x * 128;
    const int ks = blockIdx.y;
    const int kbase = ks * kchunk;

    const int n4 = kchunk >> 4;
    const int kq_mask = (kchunk >> 2) - 1;
    for (int i = 0; i < n4; ++i) {
        int idx4 = t + (i << 8);
        int r = idx4 >> kcl2;
        int kq = idx4 & kq_mask;
        int u = kbase + (kq << 2);
        float4 v = *(const float4*)(Abase + r * UU + u);
        if (Badd) {
            float4 a = *(const float4*)(Badd + r * UU + u);
            v.x += a.x; v.y += a.y; v.z += a.z; v.w += a.w;
        }
        v.x *= scale; v.y *= scale; v.z *= scale; v.w *= scale;
        int kk = kq << 2;
        At[(kk + 0) * 64 + r] = v.x;
        At[(kk + 1) * 64 + r] = v.y;
        At[(kk + 2) * 64 + r] = v.z;
        At[(kk + 3) * 64 + r] = v.w;
    }
    __syncthreads();

    const int wave = t >> 6;
    const int lane = t & 63;
    const int row0 = wave << 4;
    const int col = cb + (lane << 1);
    const bool wvalid = (col + 2 <= N);
    const float* Wp = W + (size_t)kbase * N + col;

    float acc[16][2];
    #pragma unroll
    for (int r = 0; r < 16; ++r) { acc[r][0] = 0.f; acc[r][1] = 0.f; }

    float2 wb0[8], wb1[8];
    if (wvalid) {
        #pragma unroll
        for (int i = 0; i < 8; ++i) wb0[i] = *(const float2*)(Wp + (size_t)i * N);
    }
    for (int kb = 0; kb < kchunk; kb += 8) {
        if (wvalid && (kb + 8 < kchunk)) {
            #pragma unroll
            for (int i = 0; i < 8; ++i)
                wb1[i] = *(const float2*)(Wp + (size_t)(kb + 8 + i) * N);
        }
        #pragma unroll
        for (int i = 0; i < 8; ++i) {
            const float* ap = &At[(kb + i) * 64 + row0];
            float a[16];
            *(float4*)&a[0]  = *(const float4*)(ap + 0);
            *(float4*)&a[4]  = *(const float4*)(ap + 4);
            *(float4*)&a[8]  = *(const float4*)(ap + 8);
            *(float4*)&a[12] = *(const float4*)(ap + 12);
            float2 wv = wb0[i];
            #pragma unroll
            for (int r = 0; r < 16; ++r) {
                acc[r][0] = fmaf(a[r], wv.x, acc[r][0]);
                acc[r][1] = fmaf(a[r], wv.y, acc[r][1]);
            }
        }
        #pragma unroll
        for (int i = 0; i < 8; ++i) wb0[i] = wb1[i];
    }

    if (wvalid) {
        float* dst = pbuf + (size_t)ks * 64 * N + col;
        #pragma unroll
        for (int r = 0; r < 16; ++r) {
            float2 o; o.x = acc[r][0]; o.y = acc[r][1];
            *(float2*)(dst + (size_t)(row0 + r) * N) = o;
        }
    }
}

// ---------------------------------------------------------------------------
// Fused read-softmax + read-pass + kin assembly.  grid BH, block 256.
// Block (b,h): softmax over 513 slots -> rw; g[m]=rw*P_l in LDS;
// weighted column pass over mem0[b,:,h*64..h*64+63]; kin written directly.
// ---------------------------------------------------------------------------
template <int LP>
__global__ __launch_bounds__(256) void k_smR(const float* __restrict__ pbuf,
                                             const float* __restrict__ bias,
                                             const float* __restrict__ wwall,
                                             const float* __restrict__ mem0,
                                             const float* __restrict__ nvall,
                                             const float* __restrict__ curout,
                                             float* __restrict__ kin) {
    __shared__ float g[MM];
    __shared__ float4 red[16][16];
    __shared__ float sm[4];
    __shared__ float sr[4][4];
    __shared__ float rwm_s;
    const int bh = blockIdx.x;
    const int b = bh >> 4, h = bh & 15;
    const int t = threadIdx.x;

    // ---- softmax over 513 slots (ksplit = 8 partials) ----
    float v[3];
    float mx = -1e30f;
    #pragma unroll
    for (int i = 0; i < 3; ++i) {
        int slot = t + (i << 8);
        float val = -1e30f;
        if (slot < MM + 1) {
            int j = slot * HH + h;
            val = bias[j];
            #pragma unroll
            for (int ks = 0; ks < 8; ++ks) val += pbuf[(size_t)(ks * BB + b) * NR + j];
        }
        v[i] = val;
        mx = fmaxf(mx, val);
    }
    mx = warp_reduce_max(mx);
    if ((t & 63) == 0) sm[t >> 6] = mx;
    __syncthreads();
    mx = fmaxf(fmaxf(sm[0], sm[1]), fmaxf(sm[2], sm[3]));
    __syncthreads();
    float sum = 0.f;
    #pragma unroll
    for (int i = 0; i < 3; ++i) {
        int slot = t + (i << 8);
        if (slot < MM + 1) { v[i] = __expf(v[i] - mx); sum += v[i]; }
    }
    sum = warp_reduce_sum(sum);
    if ((t & 63) == 0) sm[t >> 6] = sum;
    __syncthreads();
    sum = sm[0] + sm[1] + sm[2] + sm[3];
    const float inv = 1.0f / sum;

    // ---- per-slot weights: g[m] = rw*P_l ; racc_j = sum rw*Q_{l,j} ----
    float racc[LP > 0 ? LP : 1];
    #pragma unroll
    for (int j = 0; j < LP; ++j) racc[j] = 0.f;
    #pragma unroll
    for (int i = 0; i < 2; ++i) {
        int m = t + (i << 8);
        float p = v[i] * inv;
        float prod = 1.f;
        if (LP > 0) {
            float w[LP > 0 ? LP : 1];
            #pragma unroll
            for (int j = 0; j < LP; ++j)
                w[j] = wwall[((size_t)j * BH + bh) * MM + m];
            #pragma unroll
            for (int j = LP - 1; j >= 0; --j) {
                racc[j] += p * (w[j] * prod);
                prod *= (1.f - w[j]);
            }
        }
        g[m] = p * prod;
    }
    if (t == 0) rwm_s = v[2] * inv;      // input-slot weight
    if (LP > 0) {
        #pragma unroll
        for (int j = 0; j < LP; ++j) racc[j] = warp_reduce_sum(racc[j]);
        if ((t & 63) == 0) {
            #pragma unroll
            for (int j = 0; j < LP; ++j) sr[t >> 6][j] = racc[j];
        }
    }
    __syncthreads();

    // ---- weighted column pass over mem0[b, :, h*64 .. h*64+63] ----
    const int tc = t & 15, tg = t >> 4;
    const float4* src = (const float4*)(mem0 + (size_t)b * MM * UU);
    const int col4 = h * 16 + tc;
    float4 acc = make_float4(0.f, 0.f, 0.f, 0.f);
    for (int m = tg * 32; m < tg * 32 + 32; ++m) {
        float wgt = g[m];
        float4 mv = src[(size_t)m * 256 + col4];
        acc.x = fmaf(wgt, mv.x, acc.x); acc.y = fmaf(wgt, mv.y, acc.y);
        acc.z = fmaf(wgt, mv.z, acc.z); acc.w = fmaf(wgt, mv.w, acc.w);
    }
    red[tg][tc] = acc;
    __syncthreads();
    if (t < 16) {
        float4 o = red[0][t];
        #pragma unroll
        for (int q = 1; q < 16; ++q) {
            o.x += red[q][t].x; o.y += red[q][t].y;
            o.z += red[q][t].z; o.w += red[q][t].w;
        }
        const int u = h * 64 + t * 4;
        #pragma unroll
        for (int j = 0; j < LP; ++j) {
            float R = sr[0][j] + sr[1][j] + sr[2][j] + sr[3][j];
            float4 nv = *(const float4*)(nvall + ((size_t)(j * BB + b) << 10) + u);
            o.x = fmaf(R, nv.x, o.x); o.y = fmaf(R, nv.y, o.y);
            o.z = fmaf(R, nv.z, o.z); o.w = fmaf(R, nv.w, o.w);
        }
        float rm = rwm_s;
        float4 ov = *(const float4*)(curout + (size_t)b * UU + u);
        o.x = fmaf(rm, ov.x, o.x); o.y = fmaf(rm, ov.y, o.y);
        o.z = fmaf(rm, ov.z, o.z); o.w = fmaf(rm, ov.w, o.w);
        *(float4*)(kin + (size_t)b * UU + u) = o;
    }
}

// ---------------------------------------------------------------------------
// Fused write-softmax + colsum pass.  grid BH, block 256.
// Block (b,h): softmax over 512 slots -> ww (written to wwOut for later
// layers + k_final). If WSP: g[m]=P_{l+1}; colsum written directly.
// ---------------------------------------------------------------------------
template <int LP, int WSP>
__global__ __launch_bounds__(256) void k_smS(const float* __restrict__ pbuf,
                                             const float* __restrict__ bias,
                                             const float* __restrict__ wwall,
                                             const float* __restrict__ mem0,
                                             const float* __restrict__ nvall,
                                             float* __restrict__ wwOut,
                                             float* __restrict__ colsum) {
    __shared__ float g[MM];
    __shared__ float4 red[16][16];
    __shared__ float sm[4];
    __shared__ float sr[4][4];
    const int bh = blockIdx.x;
    const int b = bh >> 4, h = bh & 15;
    const int t = threadIdx.x;

    // ---- softmax over 512 slots (ksplit = 8 partials) ----
    float v[2];
    float mx = -1e30f;
    #pragma unroll
    for (int i = 0; i < 2; ++i) {
        int slot = t + (i << 8);
        int j = slot * HH + h;
        float val = bias[j];
        #pragma unroll
        for (int ks = 0; ks < 8; ++ks) val += pbuf[(size_t)(ks * BB + b) * NW + j];
        v[i] = val;
        mx = fmaxf(mx, val);
    }
    mx = warp_reduce_max(mx);
    if ((t & 63) == 0) sm[t >> 6] = mx;
    __syncthreads();
    mx = fmaxf(fmaxf(sm[0], sm[1]), fmaxf(sm[2], sm[3]));
    __syncthreads();
    float sum = 0.f;
    #pragma unroll
    for (int i = 0; i < 2; ++i) { v[i] = __expf(v[i] - mx); sum += v[i]; }
    sum = warp_reduce_sum(sum);
    if ((t & 63) == 0) sm[t >> 6] = sum;
    __syncthreads();
    sum = sm[0] + sm[1] + sm[2] + sm[3];
    const float inv = 1.0f / sum;

    float sacc[4] = {0.f, 0.f, 0.f, 0.f};
    #pragma unroll
    for (int i = 0; i < 2; ++i) {
        int m = t + (i << 8);
        float p = v[i] * inv;
        wwOut[(size_t)bh * MM + m] = p;
        if (WSP) {
            float prod = 1.f;
            float q[LP > 0 ? LP : 1];
            if (LP > 0) {
                float w[LP > 0 ? LP : 1];
                #pragma unroll
                for (int j = 0; j < LP; ++j)
                    w[j] = wwall[((size_t)j * BH + bh) * MM + m];
                #pragma unroll
                for (int j = LP - 1; j >= 0; --j) {
                    q[j] = w[j] * prod;
                    prod *= (1.f - w[j]);
                }
            }
            float om = 1.f - p;
            #pragma unroll
            for (int j = 0; j < LP; ++j) sacc[j] += q[j] * om;   // Q_{l+1,j}
            sacc[LP] += p;                                       // Q_{l+1,l}
            g[m] = prod * om;                                    // P_{l+1}
        }
    }
    if (!WSP) return;

    #pragma unroll
    for (int j = 0; j <= LP; ++j) sacc[j] = warp_reduce_sum(sacc[j]);
    if ((t & 63) == 0) {
        #pragma unroll
        for (int j = 0; j <= LP; ++j) sr[t >> 6][j] = sacc[j];
    }
    __syncthreads();

    // ---- colsum pass over mem0 with weight P_{l+1} ----
    const int tc = t & 15, tg = t >> 4;
    const float4* src = (const float4*)(mem0 + (size_t)b * MM * UU);
    const int col4 = h * 16 + tc;
    float4 acc = make_float4(0.f, 0.f, 0.f, 0.f);
    for (int m = tg * 32; m < tg * 32 + 32; ++m) {
        float wgt = g[m];
        float4 mv = src[(size_t)m * 256 + col4];
        acc.x = fmaf(wgt, mv.x, acc.x); acc.y = fmaf(wgt, mv.y, acc.y);
        acc.z = fmaf(wgt, mv.z, acc.z); acc.w = fmaf(wgt, mv.w, acc.w);
    }
    red[tg][tc] = acc;
    __syncthreads();
    if (t < 16) {
        float4 o = red[0][t];
        #pragma unroll
        for (int q2 = 1; q2 < 16; ++q2) {
            o.x += red[q2][t].x; o.y += red[q2][t].y;
            o.z += red[q2][t].z; o.w += red[q2][t].w;
        }
        const int u = h * 64 + t * 4;
        #pragma unroll
        for (int j = 0; j <= LP; ++j) {
            float S = sr[0][j] + sr[1][j] + sr[2][j] + sr[3][j];
            float4 nv = *(const float4*)(nvall + ((size_t)(j * BB + b) << 10) + u);
            o.x = fmaf(S, nv.x, o.x); o.y = fmaf(S, nv.y, o.y);
            o.z = fmaf(S, nv.z, o.z); o.w = fmaf(S, nv.w, o.w);
        }
        *(float4*)(colsum + (size_t)b * UU + u) = o;
    }
}

// newval = relu(sum_ks kpartials + bk); on last layer also write `out`.
__global__ void k_relu(const float* __restrict__ pbuf, const float* __restrict__ bk,
                       float* __restrict__ newval, float* __restrict__ outdst) {
    int i = blockIdx.x * 256 + threadIdx.x;
    int b = i >> 10, u = i & 1023;
    float v = bk[u];
    for (int ks = 0; ks < 32; ++ks) v += pbuf[(size_t)(ks * BB + b) * NK + u];
    v = fmaxf(v, 0.f);
    newval[i] = v;
    if (outdst) outdst[i] = v;
}

// memOut[b,m,u] = P_4*mem0 + sum_j Q_{4,j}*nv_j   (the ONLY memory write)
__global__ __launch_bounds__(256) void k_final(const float* __restrict__ mem0,
                                               const float* __restrict__ wwall,
                                               const float* __restrict__ nvall,
                                               float* __restrict__ dst) {
    const int b = blockIdx.x, mc = blockIdx.y, t = threadIdx.x;
    const int h = t >> 4;
    const float4* s4 = (const float4*)(mem0 + (size_t)b * MM * UU);
    float4* d4 = (float4*)(dst + (size_t)b * MM * UU);
    const float* w0 = wwall + ((size_t)(0 * BB + b) * HH + h) * MM;
    const float* w1 = wwall + ((size_t)(1 * BB + b) * HH + h) * MM;
    const float* w2 = wwall + ((size_t)(2 * BB + b) * HH + h) * MM;
    const float* w3 = wwall + ((size_t)(3 * BB + b) * HH + h) * MM;
    float4 n0 = *(const float4*)(nvall + ((size_t)(0 * BB + b) << 10) + t * 4);
    float4 n1 = *(const float4*)(nvall + ((size_t)(1 * BB + b) << 10) + t * 4);
    float4 n2 = *(const float4*)(nvall + ((size_t)(2 * BB + b) << 10) + t * 4);
    float4 n3 = *(const float4*)(nvall + ((size_t)(3 * BB + b) << 10) + t * 4);
    const int m0 = mc * 32;
    for (int m = m0; m < m0 + 32; ++m) {
        float a0 = w0[m], a1 = w1[m], a2 = w2[m], a3 = w3[m];
        float c3 = a3,        r3 = 1.f - a3;
        float c2 = a2 * r3,   r2 = (1.f - a2) * r3;
        float c1 = a1 * r2,   r1 = (1.f - a1) * r2;
        float c0 = a0 * r1,   p  = (1.f - a0) * r1;
        float4 v = s4[(size_t)m * 256 + t];
        float4 o;
        o.x = p * v.x; o.y = p * v.y; o.z = p * v.z; o.w = p * v.w;
        o.x = fmaf(c0, n0.x, o.x); o.y = fmaf(c0, n0.y, o.y);
        o.z = fmaf(c0, n0.z, o.z); o.w = fmaf(c0, n0.w, o.w);
        o.x = fmaf(c1, n1.x, o.x); o.y = fmaf(c1, n1.y, o.y);
        o.z = fmaf(c1, n1.z, o.z); o.w = fmaf(c1, n1.w, o.w);
        o.x = fmaf(c2, n2.x, o.x); o.y = fmaf(c2, n2.y, o.y);
        o.z = fmaf(c2, n2.z, o.z); o.w = fmaf(c2, n2.w, o.w);
        o.x = fmaf(c3, n3.x, o.x); o.y = fmaf(c3, n3.y, o.y);
        o.z = fmaf(c3, n3.z, o.z); o.w = fmaf(c3, n3.w, o.w);
        d4[(size_t)m * 256 + t] = o;
    }
}

// ---------------------------------------------------------------------------
extern "C" void kernel_launch(void* const* d_in, const int* in_sizes, int n_in,
                              void* d_out, int out_size, void* d_ws, size_t ws_size,
                              hipStream_t stream) {
    const float* x    = (const float*)d_in[0];
    const float* memI = (const float*)d_in[1];
    const float* Wr   = (const float*)d_in[2];
    const float* br   = (const float*)d_in[3];
    const float* Ww   = (const float*)d_in[4];
    const float* bw   = (const float*)d_in[5];
    const float* Wk   = (const float*)d_in[6];
    const float* bk   = (const float*)d_in[7];

    float* outp   = (float*)d_out;        // [B,U]
    float* memOut = outp + BB * UU;       // [B,M,U] — written ONCE at the end

    // workspace (~9.6 MB)
    float* wwAll  = (float*)d_ws;         // [4][B][H][M]
    float* nvAll  = wwAll + 4 * BHM;      // [4][B][U]
    float* colsum = nvAll + 4 * BU;       // [B][U]
    float* kin    = colsum + BU;          // [B][U]

    // GEMM partial buffer lives in the not-yet-written memory output region
    float* pbuf = memOut;                 // up to 8*64*8208 f32 (16.8 MB)

    k_colsum0<<<dim3(BB, 4), 256, 0, stream>>>(memI, colsum);

    for (int l = 0; l < DD; ++l) {
        const float* curOut = (l == 0) ? x : nvAll + (size_t)(l - 1) * BU;
        float* nv = nvAll + (size_t)l * BU;
        float* wwOut = wwAll + (size_t)l * BHM;

        // rlog = ((colsum + out)/513) @ Wr[l]
        k_gemm<<<dim3(65, 8), 256, 128 * 64 * 4, stream>>>(
            curOut, colsum, 1.0f / 513.0f, Wr + (size_t)l * UU * NR, pbuf, NR, 128, 5);
        switch (l) {
            case 0: k_smR<0><<<BH, 256, 0, stream>>>(pbuf, br + (size_t)l * NR, wwAll, memI, nvAll, curOut, kin); break;
            case 1: k_smR<1><<<BH, 256, 0, stream>>>(pbuf, br + (size_t)l * NR, wwAll, memI, nvAll, curOut, kin); break;
            case 2: k_smR<2><<<BH, 256, 0, stream>>>(pbuf, br + (size_t)l * NR, wwAll, memI, nvAll, curOut, kin); break;
            default: k_smR<3><<<BH, 256, 0, stream>>>(pbuf, br + (size_t)l * NR, wwAll, memI, nvAll, curOut, kin); break;
        }
        // klog = kin @ Wk[l]
        k_gemm<<<dim3(8, 32), 256, 32 * 64 * 4, stream>>>(
            kin, nullptr, 1.0f, Wk + (size_t)l * UU * NK, pbuf, NK, 32, 3);
        k_relu<<<BU / 256, 256, 0, stream>>>(pbuf, bk + (size_t)l * NK, nv,
                                             (l == DD - 1) ? outp : (float*)nullptr);
        // wlog = newval @ Ww[l]
        k_gemm<<<dim3(64, 8), 256, 128 * 64 * 4, stream>>>(
            nv, nullptr, 1.0f, Ww + (size_t)l * UU * NW, pbuf, NW, 128, 5);
        switch (l) {
            case 0: k_smS<0, 1><<<BH, 256, 0, stream>>>(pbuf, bw + (size_t)l * NW, wwAll, memI, nvAll, wwOut, colsum); break;
            case 1: k_smS<1, 1><<<BH, 256, 0, stream>>>(pbuf, bw + (size_t)l * NW, wwAll, memI, nvAll, wwOut, colsum); break;
            case 2: k_smS<2, 1><<<BH, 256, 0, stream>>>(pbuf, bw + (size_t)l * NW, wwAll, memI, nvAll, wwOut, colsum); break;
            default: k_smS<3, 0><<<BH, 256, 0, stream>>>(pbuf, bw + (size_t)l * NW, wwAll, memI, nvAll, wwOut, colsum); break;
        }
    }

    k_final<<<dim3(BB, 16), 256, 0, stream>>>(memI, wwAll, nvAll, memOut);
}